// Round 6
// baseline (213.072 us; speedup 1.0000x reference)
//
#include <hip/hip_runtime.h>
#include <hip/hip_bf16.h>

#define NN 50000
#define EE 800000
#define IN_F 128
#define HC 64
#define NEG_SLOPE 0.2f
#define BN_EPS 1e-5f
#define SCAN_NB ((NN + 1023) / 1024)   // 49 blocks of 1024 elements

#define NBKT 196          // buckets of 256 nodes: dst>>8 (max 49999>>8 = 195)
#define NBLKS 200         // sort blocks
#define EPB2 (EE / NBLKS) // 4000 edges per sort block
#define TOTH (NBKT * NBLKS)  // 39200
#define SCH 39            // ceil(39200/1024)

typedef __attribute__((ext_vector_type(8))) short short8;
typedef __attribute__((ext_vector_type(4))) float f32x4;

__device__ __forceinline__ ushort f2bf(float f) {
  uint u = __float_as_uint(f);
  uint r = u + 0x7FFF + ((u >> 16) & 1);   // RNE
  return (ushort)(r >> 16);
}
__device__ __forceinline__ float bf2f(ushort u) {
  return __uint_as_float(((uint)u) << 16);
}

// ---------------- Kernel 1: MFMA bf16 GEMM: h=x@W (bf16 out), res=x@Wres (f32), al_s, al_d --
__global__ __launch_bounds__(256) void gemm_mfma_kernel(
    const float* __restrict__ x, const float* __restrict__ W, const float* __restrict__ Wres,
    const float* __restrict__ a_src, const float* __restrict__ a_dst,
    ushort* __restrict__ h, float* __restrict__ res,
    float* __restrict__ al_s, float* __restrict__ al_d) {
  __shared__ ushort bs[128 * 128];   // [col][k] bf16, swizzled: byte ^= (col&7)<<4
  __shared__ ushort xs[64 * 128];    // [row][k] bf16, swizzled: byte ^= (row&7)<<4

  const int tid = threadIdx.x;
  const int r0 = blockIdx.x * 64;

  {
    const int c4 = (tid & 31) * 4;
    const int kb = (tid >> 5) * 16;
    const float* src0 = (c4 < HC) ? (W + c4) : (Wres + (c4 - HC));
    char* base = (char*)bs;
#pragma unroll
    for (int j = 0; j < 8; ++j) {
      int k0 = kb + j * 2;
      float4 fa = *(const float4*)(src0 + (size_t)k0 * HC);
      float4 fb = *(const float4*)(src0 + (size_t)(k0 + 1) * HC);
      uint p0 = (uint)f2bf(fa.x) | ((uint)f2bf(fb.x) << 16);
      uint p1 = (uint)f2bf(fa.y) | ((uint)f2bf(fb.y) << 16);
      uint p2 = (uint)f2bf(fa.z) | ((uint)f2bf(fb.z) << 16);
      uint p3 = (uint)f2bf(fa.w) | ((uint)f2bf(fb.w) << 16);
      *(uint*)(base + (((c4 + 0) * 256 + k0 * 2) ^ (((c4 + 0) & 7) << 4))) = p0;
      *(uint*)(base + (((c4 + 1) * 256 + k0 * 2) ^ (((c4 + 1) & 7) << 4))) = p1;
      *(uint*)(base + (((c4 + 2) * 256 + k0 * 2) ^ (((c4 + 2) & 7) << 4))) = p2;
      *(uint*)(base + (((c4 + 3) * 256 + k0 * 2) ^ (((c4 + 3) & 7) << 4))) = p3;
    }
  }
  {
    char* base = (char*)xs;
#pragma unroll
    for (int i = 0; i < 8; ++i) {
      int f4 = i * 256 + tid;
      int row = f4 >> 5;
      int kq = (f4 & 31) * 4;
      int gr = r0 + row;
      float4 v = make_float4(0.f, 0.f, 0.f, 0.f);
      if (gr < NN) v = *(const float4*)(x + (size_t)gr * IN_F + kq);
      uint lo = (uint)f2bf(v.x) | ((uint)f2bf(v.y) << 16);
      uint hi = (uint)f2bf(v.z) | ((uint)f2bf(v.w) << 16);
      uint off = (uint)((row * 256 + kq * 2) ^ ((row & 7) << 4));
      *(uint2*)(base + off) = make_uint2(lo, hi);
    }
  }
  __syncthreads();

  const int w = tid >> 6;
  const int l = tid & 63;
  const int lr = l & 15;
  const int lk = (l >> 4) * 8;

  f32x4 acc[8];
#pragma unroll
  for (int i = 0; i < 8; ++i) acc[i] = (f32x4){0.f, 0.f, 0.f, 0.f};

  const char* xb = (const char*)xs;
  const char* bb = (const char*)bs;
  const int arow = w * 16 + lr;
#pragma unroll
  for (int ks = 0; ks < 4; ++ks) {
    const int kbase = ks * 32 + lk;
    short8 af = *(const short8*)(xb + ((arow * 256 + kbase * 2) ^ ((arow & 7) << 4)));
#pragma unroll
    for (int ct = 0; ct < 8; ++ct) {
      const int c = ct * 16 + lr;
      short8 bfr = *(const short8*)(bb + ((c * 256 + kbase * 2) ^ ((c & 7) << 4)));
      acc[ct] = __builtin_amdgcn_mfma_f32_16x16x32_bf16(af, bfr, acc[ct], 0, 0, 0);
    }
  }

  const int rb = r0 + w * 16;
#pragma unroll
  for (int ct = 0; ct < 8; ++ct) {
#pragma unroll
    for (int r = 0; r < 4; ++r) {
      int gr = rb + (l >> 4) * 4 + r;
      if (gr < NN) {
        if (ct < 4) h[(size_t)gr * HC + ct * 16 + lr] = f2bf(acc[ct][r]);
        else        res[(size_t)gr * HC + (ct - 4) * 16 + lr] = acc[ct][r];
      }
    }
  }

  float myS[4] = {0.f, 0.f, 0.f, 0.f};
  float myD[4] = {0.f, 0.f, 0.f, 0.f};
#pragma unroll
  for (int ct = 0; ct < 4; ++ct) {
    float asv = a_src[ct * 16 + lr];
    float adv = a_dst[ct * 16 + lr];
#pragma unroll
    for (int r = 0; r < 4; ++r) {
      float ps = acc[ct][r] * asv;
      float pd = acc[ct][r] * adv;
      ps += __shfl_xor(ps, 1); ps += __shfl_xor(ps, 2); ps += __shfl_xor(ps, 4); ps += __shfl_xor(ps, 8);
      pd += __shfl_xor(pd, 1); pd += __shfl_xor(pd, 2); pd += __shfl_xor(pd, 4); pd += __shfl_xor(pd, 8);
      if (lr == ct) { myS[r] = ps; myD[r] = pd; }
    }
  }
  if (lr < 4) {
#pragma unroll
    for (int r = 0; r < 4; ++r) {
      int gr = rb + (l >> 4) * 4 + r;
      if (gr < NN) {
        al_s[gr * 4 + lr] = myS[r];
        al_d[gr * 4 + lr] = myD[r];
      }
    }
  }
}

// ---------------- Kernel 2: per-block bucket histogram + per-node counts ----------------
__global__ __launch_bounds__(256) void histB_kernel(const int* __restrict__ dst,
                                                    int* __restrict__ counts,
                                                    int* __restrict__ histmat) {
  __shared__ int lh[NBKT];
  const int tid = threadIdx.x;
  for (int i = tid; i < NBKT; i += 256) lh[i] = 0;
  __syncthreads();
  const int ebase = blockIdx.x * EPB2;
  for (int off = tid; off < EPB2; off += 256) {
    int d = dst[ebase + off];
    atomicAdd(&lh[d >> 8], 1);
    atomicAdd(&counts[d], 1);         // per-node degree (for row_ptr)
  }
  __syncthreads();
  for (int i = tid; i < NBKT; i += 256) histmat[i * NBLKS + blockIdx.x] = lh[i];
}

// ---------------- Kernel 3a: per-block scan of counts -> row_ptr ----------------
__global__ __launch_bounds__(256) void scan1_kernel(const int* __restrict__ counts,
                                                    int* __restrict__ row_ptr,
                                                    int* __restrict__ blk_sums) {
  const int tid = threadIdx.x;
  const int base = blockIdx.x * 1024 + tid * 4;
  int4 v = make_int4(0, 0, 0, 0);
  if (base + 3 < NN) {
    v = *(const int4*)&counts[base];
  } else {
    if (base + 0 < NN) v.x = counts[base + 0];
    if (base + 1 < NN) v.y = counts[base + 1];
    if (base + 2 < NN) v.z = counts[base + 2];
    if (base + 3 < NN) v.w = counts[base + 3];
  }
  const int s = v.x + v.y + v.z + v.w;
  const int lane = tid & 63;
  const int wave = tid >> 6;
  int incl = s;
#pragma unroll
  for (int off = 1; off < 64; off <<= 1) {
    int t = __shfl_up(incl, off);
    if (lane >= off) incl += t;
  }
  __shared__ int wsum[4];
  if (lane == 63) wsum[wave] = incl;
  __syncthreads();
  int woff = 0;
  for (int w = 0; w < wave; ++w) woff += wsum[w];
  const int excl = woff + incl - s;
  int4 o;
  o.x = excl;
  o.y = o.x + v.x;
  o.z = o.y + v.y;
  o.w = o.z + v.z;
  if (base + 3 < NN) {
    *(int4*)&row_ptr[base] = o;
  } else {
    if (base + 0 < NN) row_ptr[base + 0] = o.x;
    if (base + 1 < NN) row_ptr[base + 1] = o.y;
    if (base + 2 < NN) row_ptr[base + 2] = o.z;
    if (base + 3 < NN) row_ptr[base + 3] = o.w;
  }
  if (tid == 255) blk_sums[blockIdx.x] = woff + incl;
}

// ---------------- Kernel 3b: scan of block sums (single wave) ----------------
__global__ __launch_bounds__(64) void scan2_kernel(int* __restrict__ blk_sums,
                                                   int* __restrict__ row_ptr) {
  const int lane = threadIdx.x;
  int v = (lane < SCAN_NB) ? blk_sums[lane] : 0;
  int incl = v;
#pragma unroll
  for (int off = 1; off < 64; off <<= 1) {
    int t = __shfl_up(incl, off);
    if (lane >= off) incl += t;
  }
  if (lane < SCAN_NB) blk_sums[lane] = incl - v;
  if (lane == 63) row_ptr[NN] = incl;
}

// ---------------- Kernel 3c: finalize row_ptr ----------------
__global__ __launch_bounds__(256) void scan3_kernel(int* __restrict__ row_ptr,
                                                    const int* __restrict__ blk_sums) {
  int i = blockIdx.x * 256 + threadIdx.x;
  if (i < NN) row_ptr[i] += blk_sums[i >> 10];
}

// ---------------- Kernel 4: scan histmat (bucket-major) -> per-(bucket,block) bases ----
// 39200 ints, one 1024-thread block: serial per-thread sums + wave-shuffle scan.
__global__ __launch_bounds__(1024) void scanH_kernel(int* __restrict__ histmat,
                                                     int* __restrict__ bucket_base) {
  const int tid = threadIdx.x;
  const int beg = tid * SCH;
  const int end = (beg + SCH < TOTH) ? beg + SCH : TOTH;
  int s = 0;
  for (int i = beg; i < end; ++i) s += histmat[i];   // pass 1 (L2-hot)
  const int lane = tid & 63;
  const int wv = tid >> 6;
  int incl = s;
#pragma unroll
  for (int off = 1; off < 64; off <<= 1) {
    int t = __shfl_up(incl, off);
    if (lane >= off) incl += t;
  }
  __shared__ int wsum[16];
  if (lane == 63) wsum[wv] = incl;
  __syncthreads();
  int woff = 0;
  for (int w = 0; w < wv; ++w) woff += wsum[w];
  int ex = woff + incl - s;     // exclusive prefix of this thread's range
  for (int i = beg; i < end; ++i) {  // pass 2: write back exclusive scan
    int v = histmat[i];
    histmat[i] = ex;
    if ((i % NBLKS) == 0) bucket_base[i / NBLKS] = ex;
    ex += v;
  }
  if (tid == 1023) bucket_base[NBKT] = EE;
}

// ---------------- Kernel 5: place edges into bucket-sorted pairs ----------------
// LDS cursor per bucket; each (block,bucket) output region is contiguous ->
// every pairs cache line is produced by exactly one block (one XCD): no write amp.
__global__ __launch_bounds__(256) void placeB_kernel(const int* __restrict__ src,
                                                     const int* __restrict__ dst,
                                                     const int* __restrict__ histmat,
                                                     uint* __restrict__ pairs) {
  __shared__ int cur[NBKT];
  const int tid = threadIdx.x;
  for (int i = tid; i < NBKT; i += 256) cur[i] = histmat[i * NBLKS + blockIdx.x];
  __syncthreads();
  const int ebase = blockIdx.x * EPB2;
  for (int off = tid; off < EPB2; off += 256) {
    const int e = ebase + off;
    const int d = dst[e];
    const uint val = ((uint)(d & 255) << 16) | (uint)src[e];
    int p = atomicAdd(&cur[d >> 8], 1);
    pairs[p] = val;
  }
}

// ---------------- Kernel 6: fine scatter within bucket (LDS cursors) ----------------
__global__ __launch_bounds__(256) void bscatter_kernel(const uint* __restrict__ pairs,
                                                       const int* __restrict__ row_ptr,
                                                       const int* __restrict__ bucket_base,
                                                       int* __restrict__ col) {
  __shared__ int cur[256];
  const int b = blockIdx.x;
  const int tid = threadIdx.x;
  const int node = (b << 8) + tid;
  cur[tid] = (node < NN) ? row_ptr[node] : 0;
  __syncthreads();
  const int lo = bucket_base[b];
  const int hi = bucket_base[b + 1];
  for (int i = lo + tid; i < hi; i += 256) {
    uint v = pairs[i];
    int d = (v >> 16) & 255;
    int p = atomicAdd(&cur[d], 1);
    col[p] = (int)(v & 0xFFFFu);
  }
}

// ---------------- Kernel 7: per-node aggregate (wave per node) ----------------
__global__ __launch_bounds__(256) void node_kernel(
    const ushort* __restrict__ h, const float* __restrict__ al_s, const float* __restrict__ al_d,
    const int* __restrict__ row_ptr, const int* __restrict__ col,
    float* __restrict__ out_pre) {
  const int node = blockIdx.x * 4 + (threadIdx.x >> 6);
  const int lane = threadIdx.x & 63;
  const int head = lane >> 4;

  const float ald = al_d[node * 4 + head];
  float e0 = al_s[node * 4 + head] + ald;   // self loop
  e0 = e0 > 0.f ? e0 : NEG_SLOPE * e0;
  float m = __expf(e0);
  float denom = m;
  float acc = m * bf2f(h[(size_t)node * HC + lane]);

  const int beg = row_ptr[node];
  const int end = row_ptr[node + 1];
  int idx = beg;
  for (; idx + 8 <= end; idx += 8) {
    int s[8]; float as[8]; float hv[8];
#pragma unroll
    for (int u = 0; u < 8; ++u) s[u] = col[idx + u];
#pragma unroll
    for (int u = 0; u < 8; ++u) as[u] = al_s[s[u] * 4 + head];
#pragma unroll
    for (int u = 0; u < 8; ++u) hv[u] = bf2f(h[(size_t)s[u] * HC + lane]);
#pragma unroll
    for (int u = 0; u < 8; ++u) {
      float ee = as[u] + ald;
      ee = ee > 0.f ? ee : NEG_SLOPE * ee;
      float mm = __expf(ee);
      denom += mm;
      acc = fmaf(mm, hv[u], acc);
    }
  }
  for (; idx < end; ++idx) {
    int s = col[idx];
    float ee = al_s[s * 4 + head] + ald;
    ee = ee > 0.f ? ee : NEG_SLOPE * ee;
    float mm = __expf(ee);
    denom += mm;
    acc = fmaf(mm, bf2f(h[(size_t)s * HC + lane]), acc);
  }
  out_pre[(size_t)node * HC + lane] = acc / denom;
}

// ---------------- Kernel 8: BN statistics ----------------
__global__ __launch_bounds__(256) void stats_kernel(const float* __restrict__ out_pre,
                                                    float* __restrict__ sums) {
  const int c = threadIdx.x & 63;
  const int rg = threadIdx.x >> 6;
  float s = 0.f, s2 = 0.f;
  for (int r = blockIdx.x * 4 + rg; r < NN; r += gridDim.x * 4) {
    float v = out_pre[(size_t)r * HC + c];
    s += v;
    s2 = fmaf(v, v, s2);
  }
  __shared__ float lds[512];
  lds[threadIdx.x] = s;
  lds[256 + threadIdx.x] = s2;
  __syncthreads();
  if (threadIdx.x < 64) {
    float ts = lds[c] + lds[64 + c] + lds[128 + c] + lds[192 + c];
    float t2 = lds[256 + c] + lds[256 + 64 + c] + lds[256 + 128 + c] + lds[256 + 192 + c];
    atomicAdd(&sums[c], ts);
    atomicAdd(&sums[64 + c], t2);
  }
}

// ---------------- Kernel 9: BN + ELU + residual ----------------
__global__ __launch_bounds__(256) void final_kernel(
    const float* __restrict__ out_pre, const float* __restrict__ res,
    const float* __restrict__ sums, const float* __restrict__ gamma,
    const float* __restrict__ beta, float* __restrict__ out) {
  const int i = blockIdx.x * 256 + threadIdx.x;
  const int c = i & 63;
  const float inv_n = 1.0f / (float)NN;
  float mu = sums[c] * inv_n;
  float var = sums[64 + c] * inv_n - mu * mu;
  float rinv = rsqrtf(var + BN_EPS);
  float v = (out_pre[i] - mu) * rinv * gamma[c] + beta[c];
  v = v > 0.f ? v : (__expf(v) - 1.0f);
  out[i] = v + res[i];
}

extern "C" void kernel_launch(void* const* d_in, const int* in_sizes, int n_in,
                              void* d_out, int out_size, void* d_ws, size_t ws_size,
                              hipStream_t stream) {
  const float* x     = (const float*)d_in[0];
  const int*   ei    = (const int*)d_in[1];     // [2,E]: src = ei, dst = ei+E
  const float* W     = (const float*)d_in[2];
  const float* a_src = (const float*)d_in[3];
  const float* a_dst = (const float*)d_in[4];
  // d_in[5] = bias: cancels exactly through BatchNorm mean-subtraction -> unused
  const float* gamma = (const float*)d_in[6];
  const float* beta  = (const float*)d_in[7];
  const float* Wres  = (const float*)d_in[8];
  float* out = (float*)d_out;

  char* ws = (char*)d_ws;
  ushort* h        = (ushort*)ws; ws += (size_t)NN * HC * 2;   // bf16 h
  float* resb      = (float*)ws;  ws += (size_t)NN * HC * 4;
  float* out_pre   = (float*)ws;  ws += (size_t)NN * HC * 4;
  float* al_s      = (float*)ws;  ws += (size_t)NN * 4 * 4;
  float* al_d      = (float*)ws;  ws += (size_t)NN * 4 * 4;
  float* sums      = (float*)ws;  ws += 128 * 4;               // [0:64]=sum, [64:128]=sumsq
  int*   counts    = (int*)ws;    ws += (size_t)NN * 4;        // contiguous with sums: one memset
  int*   row_ptr   = (int*)ws;    ws += (size_t)(NN + 1) * 4;
  int*   blk_sums  = (int*)ws;    ws += 64 * 4;
  int*   histmat   = (int*)ws;    ws += (size_t)TOTH * 4;      // [bucket][block]
  int*   bucket_base = (int*)ws;  ws += (NBKT + 1) * 4;
  uint*  pairs     = (uint*)ws;   ws += (size_t)EE * 4;
  int*   col       = (int*)ws;    ws += (size_t)EE * 4;

  hipMemsetAsync(sums, 0, (128 + NN) * sizeof(int), stream);

  gemm_mfma_kernel<<<(NN + 63) / 64, 256, 0, stream>>>(x, W, Wres, a_src, a_dst,
                                                       h, resb, al_s, al_d);
  histB_kernel<<<NBLKS, 256, 0, stream>>>(ei + EE, counts, histmat);
  scan1_kernel<<<SCAN_NB, 256, 0, stream>>>(counts, row_ptr, blk_sums);
  scan2_kernel<<<1, 64, 0, stream>>>(blk_sums, row_ptr);
  scan3_kernel<<<(NN + 255) / 256, 256, 0, stream>>>(row_ptr, blk_sums);
  scanH_kernel<<<1, 1024, 0, stream>>>(histmat, bucket_base);
  placeB_kernel<<<NBLKS, 256, 0, stream>>>(ei, ei + EE, histmat, pairs);
  bscatter_kernel<<<NBKT, 256, 0, stream>>>(pairs, row_ptr, bucket_base, col);
  node_kernel<<<NN / 4, 256, 0, stream>>>(h, al_s, al_d, row_ptr, col, out_pre);
  stats_kernel<<<256, 256, 0, stream>>>(out_pre, sums);
  final_kernel<<<NN * HC / 256, 256, 0, stream>>>(out_pre, resb, sums, gamma, beta, out);
}

// Round 7
// 157.683 us; speedup vs baseline: 1.3513x; 1.3513x over previous
//
#include <hip/hip_runtime.h>
#include <hip/hip_bf16.h>

#define NN 50000
#define EE 800000
#define IN_F 128
#define HC 64
#define NEG_SLOPE 0.2f
#define BN_EPS 1e-5f
#define SCAN_NB ((NN + 1023) / 1024)   // 49 blocks of 1024 elements

#define NBKT 196          // buckets of 256 nodes: dst>>8 (max 49999>>8 = 195)
#define NBLKS 200         // sort blocks
#define EPB2 (EE / NBLKS) // 4000 edges per sort block
#define TOTH (NBKT * NBLKS)  // 39200

typedef __attribute__((ext_vector_type(8))) short short8;
typedef __attribute__((ext_vector_type(4))) float f32x4;

__device__ __forceinline__ ushort f2bf(float f) {
  uint u = __float_as_uint(f);
  uint r = u + 0x7FFF + ((u >> 16) & 1);   // RNE
  return (ushort)(r >> 16);
}
__device__ __forceinline__ float bf2f(ushort u) {
  return __uint_as_float(((uint)u) << 16);
}

// ---------------- Kernel 1: MFMA bf16 GEMM: h=x@W (bf16 out), res=x@Wres (f32), al_s, al_d --
__global__ __launch_bounds__(256) void gemm_mfma_kernel(
    const float* __restrict__ x, const float* __restrict__ W, const float* __restrict__ Wres,
    const float* __restrict__ a_src, const float* __restrict__ a_dst,
    ushort* __restrict__ h, float* __restrict__ res,
    float* __restrict__ al_s, float* __restrict__ al_d) {
  __shared__ ushort bs[128 * 128];   // [col][k] bf16, swizzled: byte ^= (col&7)<<4
  __shared__ ushort xs[64 * 128];    // [row][k] bf16, swizzled: byte ^= (row&7)<<4

  const int tid = threadIdx.x;
  const int r0 = blockIdx.x * 64;

  {
    const int c4 = (tid & 31) * 4;
    const int kb = (tid >> 5) * 16;
    const float* src0 = (c4 < HC) ? (W + c4) : (Wres + (c4 - HC));
    char* base = (char*)bs;
#pragma unroll
    for (int j = 0; j < 8; ++j) {
      int k0 = kb + j * 2;
      float4 fa = *(const float4*)(src0 + (size_t)k0 * HC);
      float4 fb = *(const float4*)(src0 + (size_t)(k0 + 1) * HC);
      uint p0 = (uint)f2bf(fa.x) | ((uint)f2bf(fb.x) << 16);
      uint p1 = (uint)f2bf(fa.y) | ((uint)f2bf(fb.y) << 16);
      uint p2 = (uint)f2bf(fa.z) | ((uint)f2bf(fb.z) << 16);
      uint p3 = (uint)f2bf(fa.w) | ((uint)f2bf(fb.w) << 16);
      *(uint*)(base + (((c4 + 0) * 256 + k0 * 2) ^ (((c4 + 0) & 7) << 4))) = p0;
      *(uint*)(base + (((c4 + 1) * 256 + k0 * 2) ^ (((c4 + 1) & 7) << 4))) = p1;
      *(uint*)(base + (((c4 + 2) * 256 + k0 * 2) ^ (((c4 + 2) & 7) << 4))) = p2;
      *(uint*)(base + (((c4 + 3) * 256 + k0 * 2) ^ (((c4 + 3) & 7) << 4))) = p3;
    }
  }
  {
    char* base = (char*)xs;
#pragma unroll
    for (int i = 0; i < 8; ++i) {
      int f4 = i * 256 + tid;
      int row = f4 >> 5;
      int kq = (f4 & 31) * 4;
      int gr = r0 + row;
      float4 v = make_float4(0.f, 0.f, 0.f, 0.f);
      if (gr < NN) v = *(const float4*)(x + (size_t)gr * IN_F + kq);
      uint lo = (uint)f2bf(v.x) | ((uint)f2bf(v.y) << 16);
      uint hi = (uint)f2bf(v.z) | ((uint)f2bf(v.w) << 16);
      uint off = (uint)((row * 256 + kq * 2) ^ ((row & 7) << 4));
      *(uint2*)(base + off) = make_uint2(lo, hi);
    }
  }
  __syncthreads();

  const int w = tid >> 6;
  const int l = tid & 63;
  const int lr = l & 15;
  const int lk = (l >> 4) * 8;

  f32x4 acc[8];
#pragma unroll
  for (int i = 0; i < 8; ++i) acc[i] = (f32x4){0.f, 0.f, 0.f, 0.f};

  const char* xb = (const char*)xs;
  const char* bb = (const char*)bs;
  const int arow = w * 16 + lr;
#pragma unroll
  for (int ks = 0; ks < 4; ++ks) {
    const int kbase = ks * 32 + lk;
    short8 af = *(const short8*)(xb + ((arow * 256 + kbase * 2) ^ ((arow & 7) << 4)));
#pragma unroll
    for (int ct = 0; ct < 8; ++ct) {
      const int c = ct * 16 + lr;
      short8 bfr = *(const short8*)(bb + ((c * 256 + kbase * 2) ^ ((c & 7) << 4)));
      acc[ct] = __builtin_amdgcn_mfma_f32_16x16x32_bf16(af, bfr, acc[ct], 0, 0, 0);
    }
  }

  const int rb = r0 + w * 16;
#pragma unroll
  for (int ct = 0; ct < 8; ++ct) {
#pragma unroll
    for (int r = 0; r < 4; ++r) {
      int gr = rb + (l >> 4) * 4 + r;
      if (gr < NN) {
        if (ct < 4) h[(size_t)gr * HC + ct * 16 + lr] = f2bf(acc[ct][r]);
        else        res[(size_t)gr * HC + (ct - 4) * 16 + lr] = acc[ct][r];
      }
    }
  }

  float myS[4] = {0.f, 0.f, 0.f, 0.f};
  float myD[4] = {0.f, 0.f, 0.f, 0.f};
#pragma unroll
  for (int ct = 0; ct < 4; ++ct) {
    float asv = a_src[ct * 16 + lr];
    float adv = a_dst[ct * 16 + lr];
#pragma unroll
    for (int r = 0; r < 4; ++r) {
      float ps = acc[ct][r] * asv;
      float pd = acc[ct][r] * adv;
      ps += __shfl_xor(ps, 1); ps += __shfl_xor(ps, 2); ps += __shfl_xor(ps, 4); ps += __shfl_xor(ps, 8);
      pd += __shfl_xor(pd, 1); pd += __shfl_xor(pd, 2); pd += __shfl_xor(pd, 4); pd += __shfl_xor(pd, 8);
      if (lr == ct) { myS[r] = ps; myD[r] = pd; }
    }
  }
  if (lr < 4) {
#pragma unroll
    for (int r = 0; r < 4; ++r) {
      int gr = rb + (l >> 4) * 4 + r;
      if (gr < NN) {
        al_s[gr * 4 + lr] = myS[r];
        al_d[gr * 4 + lr] = myD[r];
      }
    }
  }
}

// ---------------- Kernel 2: per-block bucket histogram + per-node counts ----------------
__global__ __launch_bounds__(256) void histB_kernel(const int* __restrict__ dst,
                                                    int* __restrict__ counts,
                                                    int* __restrict__ histmat) {
  __shared__ int lh[NBKT];
  const int tid = threadIdx.x;
  for (int i = tid; i < NBKT; i += 256) lh[i] = 0;
  __syncthreads();
  const int ebase = blockIdx.x * EPB2;
  for (int off = tid; off < EPB2; off += 256) {
    int d = dst[ebase + off];
    atomicAdd(&lh[d >> 8], 1);
    atomicAdd(&counts[d], 1);         // per-node degree (for row_ptr)
  }
  __syncthreads();
  for (int i = tid; i < NBKT; i += 256) histmat[i * NBLKS + blockIdx.x] = lh[i];
}

// ---------------- Kernel 3a: per-block scan of counts -> row_ptr ----------------
__global__ __launch_bounds__(256) void scan1_kernel(const int* __restrict__ counts,
                                                    int* __restrict__ row_ptr,
                                                    int* __restrict__ blk_sums) {
  const int tid = threadIdx.x;
  const int base = blockIdx.x * 1024 + tid * 4;
  int4 v = make_int4(0, 0, 0, 0);
  if (base + 3 < NN) {
    v = *(const int4*)&counts[base];
  } else {
    if (base + 0 < NN) v.x = counts[base + 0];
    if (base + 1 < NN) v.y = counts[base + 1];
    if (base + 2 < NN) v.z = counts[base + 2];
    if (base + 3 < NN) v.w = counts[base + 3];
  }
  const int s = v.x + v.y + v.z + v.w;
  const int lane = tid & 63;
  const int wave = tid >> 6;
  int incl = s;
#pragma unroll
  for (int off = 1; off < 64; off <<= 1) {
    int t = __shfl_up(incl, off);
    if (lane >= off) incl += t;
  }
  __shared__ int wsum[4];
  if (lane == 63) wsum[wave] = incl;
  __syncthreads();
  int woff = 0;
  for (int w = 0; w < wave; ++w) woff += wsum[w];
  const int excl = woff + incl - s;
  int4 o;
  o.x = excl;
  o.y = o.x + v.x;
  o.z = o.y + v.y;
  o.w = o.z + v.z;
  if (base + 3 < NN) {
    *(int4*)&row_ptr[base] = o;
  } else {
    if (base + 0 < NN) row_ptr[base + 0] = o.x;
    if (base + 1 < NN) row_ptr[base + 1] = o.y;
    if (base + 2 < NN) row_ptr[base + 2] = o.z;
    if (base + 3 < NN) row_ptr[base + 3] = o.w;
  }
  if (tid == 255) blk_sums[blockIdx.x] = woff + incl;
}

// ---------------- Kernel 3b: scan of block sums (single wave) ----------------
__global__ __launch_bounds__(64) void scan2_kernel(int* __restrict__ blk_sums,
                                                   int* __restrict__ row_ptr) {
  const int lane = threadIdx.x;
  int v = (lane < SCAN_NB) ? blk_sums[lane] : 0;
  int incl = v;
#pragma unroll
  for (int off = 1; off < 64; off <<= 1) {
    int t = __shfl_up(incl, off);
    if (lane >= off) incl += t;
  }
  if (lane < SCAN_NB) blk_sums[lane] = incl - v;
  if (lane == 63) row_ptr[NN] = incl;
}

// ---------------- Kernel 3c: finalize row_ptr ----------------
__global__ __launch_bounds__(256) void scan3_kernel(int* __restrict__ row_ptr,
                                                    const int* __restrict__ blk_sums) {
  int i = blockIdx.x * 256 + threadIdx.x;
  if (i < NN) row_ptr[i] += blk_sums[i >> 10];
}

// ---------------- Kernel 4: per-bucket scan of histmat rows (196 independent blocks) ----
// bucket_base[b] == row_ptr[b<<8] (bucket regions in pairs ARE the CSR regions grouped
// by 256 nodes), so seed each row-scan with row_ptr and skip any global scan.
__global__ __launch_bounds__(256) void scanHB_kernel(int* __restrict__ histmat,
                                                     const int* __restrict__ row_ptr) {
  const int b = blockIdx.x;
  const int tid = threadIdx.x;
  int v = (tid < NBLKS) ? histmat[b * NBLKS + tid] : 0;
  const int lane = tid & 63;
  const int wv = tid >> 6;
  int incl = v;
#pragma unroll
  for (int off = 1; off < 64; off <<= 1) {
    int t = __shfl_up(incl, off);
    if (lane >= off) incl += t;
  }
  __shared__ int wsum[4];
  if (lane == 63) wsum[wv] = incl;
  __syncthreads();
  int woff = 0;
  for (int w = 0; w < wv; ++w) woff += wsum[w];
  if (tid < NBLKS)
    histmat[b * NBLKS + tid] = row_ptr[b << 8] + woff + incl - v;   // exclusive + base
}

// ---------------- Kernel 5: place edges into bucket-sorted pairs ----------------
// LDS cursor per bucket; each (block,bucket) output region is contiguous ->
// every pairs cache line is produced by exactly one block (one XCD): no write amp.
__global__ __launch_bounds__(256) void placeB_kernel(const int* __restrict__ src,
                                                     const int* __restrict__ dst,
                                                     const int* __restrict__ histmat,
                                                     uint* __restrict__ pairs) {
  __shared__ int cur[NBKT];
  const int tid = threadIdx.x;
  for (int i = tid; i < NBKT; i += 256) cur[i] = histmat[i * NBLKS + blockIdx.x];
  __syncthreads();
  const int ebase = blockIdx.x * EPB2;
  for (int off = tid; off < EPB2; off += 256) {
    const int e = ebase + off;
    const int d = dst[e];
    const uint val = ((uint)(d & 255) << 16) | (uint)src[e];
    int p = atomicAdd(&cur[d >> 8], 1);
    pairs[p] = val;
  }
}

// ---------------- Kernel 6: fine scatter within bucket (LDS cursors) ----------------
__global__ __launch_bounds__(256) void bscatter_kernel(const uint* __restrict__ pairs,
                                                       const int* __restrict__ row_ptr,
                                                       int* __restrict__ col) {
  __shared__ int cur[256];
  const int b = blockIdx.x;
  const int tid = threadIdx.x;
  const int node = (b << 8) + tid;
  cur[tid] = (node < NN) ? row_ptr[node] : 0;
  __syncthreads();
  const int lo = row_ptr[b << 8];
  const int nhi = ((b + 1) << 8) < NN ? ((b + 1) << 8) : NN;
  const int hi = row_ptr[nhi];
  for (int i = lo + tid; i < hi; i += 256) {
    uint v = pairs[i];
    int d = (v >> 16) & 255;
    int p = atomicAdd(&cur[d], 1);
    col[p] = (int)(v & 0xFFFFu);
  }
}

// ---------------- Kernel 7: per-node aggregate (wave per node) ----------------
__global__ __launch_bounds__(256) void node_kernel(
    const ushort* __restrict__ h, const float* __restrict__ al_s, const float* __restrict__ al_d,
    const int* __restrict__ row_ptr, const int* __restrict__ col,
    float* __restrict__ out_pre) {
  const int node = blockIdx.x * 4 + (threadIdx.x >> 6);
  const int lane = threadIdx.x & 63;
  const int head = lane >> 4;

  const float ald = al_d[node * 4 + head];
  float e0 = al_s[node * 4 + head] + ald;   // self loop
  e0 = e0 > 0.f ? e0 : NEG_SLOPE * e0;
  float m = __expf(e0);
  float denom = m;
  float acc = m * bf2f(h[(size_t)node * HC + lane]);

  const int beg = row_ptr[node];
  const int end = row_ptr[node + 1];
  int idx = beg;
  for (; idx + 8 <= end; idx += 8) {
    int s[8]; float as[8]; float hv[8];
#pragma unroll
    for (int u = 0; u < 8; ++u) s[u] = col[idx + u];
#pragma unroll
    for (int u = 0; u < 8; ++u) as[u] = al_s[s[u] * 4 + head];
#pragma unroll
    for (int u = 0; u < 8; ++u) hv[u] = bf2f(h[(size_t)s[u] * HC + lane]);
#pragma unroll
    for (int u = 0; u < 8; ++u) {
      float ee = as[u] + ald;
      ee = ee > 0.f ? ee : NEG_SLOPE * ee;
      float mm = __expf(ee);
      denom += mm;
      acc = fmaf(mm, hv[u], acc);
    }
  }
  for (; idx < end; ++idx) {
    int s = col[idx];
    float ee = al_s[s * 4 + head] + ald;
    ee = ee > 0.f ? ee : NEG_SLOPE * ee;
    float mm = __expf(ee);
    denom += mm;
    acc = fmaf(mm, bf2f(h[(size_t)s * HC + lane]), acc);
  }
  out_pre[(size_t)node * HC + lane] = acc / denom;
}

// ---------------- Kernel 8: BN statistics ----------------
__global__ __launch_bounds__(256) void stats_kernel(const float* __restrict__ out_pre,
                                                    float* __restrict__ sums) {
  const int c = threadIdx.x & 63;
  const int rg = threadIdx.x >> 6;
  float s = 0.f, s2 = 0.f;
  for (int r = blockIdx.x * 4 + rg; r < NN; r += gridDim.x * 4) {
    float v = out_pre[(size_t)r * HC + c];
    s += v;
    s2 = fmaf(v, v, s2);
  }
  __shared__ float lds[512];
  lds[threadIdx.x] = s;
  lds[256 + threadIdx.x] = s2;
  __syncthreads();
  if (threadIdx.x < 64) {
    float ts = lds[c] + lds[64 + c] + lds[128 + c] + lds[192 + c];
    float t2 = lds[256 + c] + lds[256 + 64 + c] + lds[256 + 128 + c] + lds[256 + 192 + c];
    atomicAdd(&sums[c], ts);
    atomicAdd(&sums[64 + c], t2);
  }
}

// ---------------- Kernel 9: BN + ELU + residual ----------------
__global__ __launch_bounds__(256) void final_kernel(
    const float* __restrict__ out_pre, const float* __restrict__ res,
    const float* __restrict__ sums, const float* __restrict__ gamma,
    const float* __restrict__ beta, float* __restrict__ out) {
  const int i = blockIdx.x * 256 + threadIdx.x;
  const int c = i & 63;
  const float inv_n = 1.0f / (float)NN;
  float mu = sums[c] * inv_n;
  float var = sums[64 + c] * inv_n - mu * mu;
  float rinv = rsqrtf(var + BN_EPS);
  float v = (out_pre[i] - mu) * rinv * gamma[c] + beta[c];
  v = v > 0.f ? v : (__expf(v) - 1.0f);
  out[i] = v + res[i];
}

extern "C" void kernel_launch(void* const* d_in, const int* in_sizes, int n_in,
                              void* d_out, int out_size, void* d_ws, size_t ws_size,
                              hipStream_t stream) {
  const float* x     = (const float*)d_in[0];
  const int*   ei    = (const int*)d_in[1];     // [2,E]: src = ei, dst = ei+E
  const float* W     = (const float*)d_in[2];
  const float* a_src = (const float*)d_in[3];
  const float* a_dst = (const float*)d_in[4];
  // d_in[5] = bias: cancels exactly through BatchNorm mean-subtraction -> unused
  const float* gamma = (const float*)d_in[6];
  const float* beta  = (const float*)d_in[7];
  const float* Wres  = (const float*)d_in[8];
  float* out = (float*)d_out;

  char* ws = (char*)d_ws;
  ushort* h        = (ushort*)ws; ws += (size_t)NN * HC * 2;   // bf16 h
  float* resb      = (float*)ws;  ws += (size_t)NN * HC * 4;
  float* out_pre   = (float*)ws;  ws += (size_t)NN * HC * 4;
  float* al_s      = (float*)ws;  ws += (size_t)NN * 4 * 4;
  float* al_d      = (float*)ws;  ws += (size_t)NN * 4 * 4;
  float* sums      = (float*)ws;  ws += 128 * 4;               // [0:64]=sum, [64:128]=sumsq
  int*   counts    = (int*)ws;    ws += (size_t)NN * 4;        // contiguous with sums: one memset
  int*   row_ptr   = (int*)ws;    ws += (size_t)(NN + 1) * 4;
  int*   blk_sums  = (int*)ws;    ws += 64 * 4;
  int*   histmat   = (int*)ws;    ws += (size_t)TOTH * 4;      // [bucket][block]
  uint*  pairs     = (uint*)ws;   ws += (size_t)EE * 4;
  int*   col       = (int*)ws;    ws += (size_t)EE * 4;

  hipMemsetAsync(sums, 0, (128 + NN) * sizeof(int), stream);

  gemm_mfma_kernel<<<(NN + 63) / 64, 256, 0, stream>>>(x, W, Wres, a_src, a_dst,
                                                       h, resb, al_s, al_d);
  histB_kernel<<<NBLKS, 256, 0, stream>>>(ei + EE, counts, histmat);
  scan1_kernel<<<SCAN_NB, 256, 0, stream>>>(counts, row_ptr, blk_sums);
  scan2_kernel<<<1, 64, 0, stream>>>(blk_sums, row_ptr);
  scan3_kernel<<<(NN + 255) / 256, 256, 0, stream>>>(row_ptr, blk_sums);
  scanHB_kernel<<<NBKT, 256, 0, stream>>>(histmat, row_ptr);
  placeB_kernel<<<NBLKS, 256, 0, stream>>>(ei, ei + EE, histmat, pairs);
  bscatter_kernel<<<NBKT, 256, 0, stream>>>(pairs, row_ptr, col);
  node_kernel<<<NN / 4, 256, 0, stream>>>(h, al_s, al_d, row_ptr, col, out_pre);
  stats_kernel<<<256, 256, 0, stream>>>(out_pre, sums);
  final_kernel<<<NN * HC / 256, 256, 0, stream>>>(out_pre, resb, sums, gamma, beta, out);
}